// Round 1
// baseline (1564.887 us; speedup 1.0000x reference)
//
#include <hip/hip_runtime.h>
#include <math.h>

#define BB   8
#define CC   256
#define NN   4096
#define DQK  32
#define SCALE 0.17677669529663687f   // 1/sqrt(32)

typedef __bf16 bf16x8 __attribute__((ext_vector_type(8)));
typedef float  f32x4  __attribute__((ext_vector_type(4)));

__device__ __forceinline__ unsigned short f2bf(float x) {
    unsigned int u = __builtin_bit_cast(unsigned int, x);
    u = (u + 0x7fffu + ((u >> 16) & 1u)) >> 16;   // RNE
    return (unsigned short)u;
}
__device__ __forceinline__ float bf2f(unsigned short h) {
    unsigned int u = ((unsigned int)h) << 16;
    return __builtin_bit_cast(float, u);
}

// ---------------------------------------------------------------------------
// K1: QKV projections. grid (NN/64, BB), block 256 = 64 n-lanes x 4 groups.
// q,k -> fp32 ws laid out [b][d][n] (d-major so K2 reads q with uniform index).
// v   -> bf16 ws [b][c][n] (MFMA A-operand layout for K3).
// ---------------------------------------------------------------------------
__global__ __launch_bounds__(256) void k_qkv(
    const float* __restrict__ sk, const float* __restrict__ ex,
    const float* __restrict__ Wq, const float* __restrict__ bq,
    const float* __restrict__ Wk, const float* __restrict__ bk,
    const float* __restrict__ Wv, const float* __restrict__ bv,
    float* __restrict__ qw, float* __restrict__ kw,
    unsigned short* __restrict__ vw)
{
    const int t  = threadIdx.x;
    const int nl = t & 63;
    const int g  = __builtin_amdgcn_readfirstlane(t >> 6);  // wave-uniform group
    const int b  = blockIdx.y;
    const int n  = blockIdx.x * 64 + nl;
    const float* skb = sk + (size_t)b * CC * NN + n;
    const float* exb = ex + (size_t)b * CC * NN + n;

    // ---- q: outputs o = g*8 .. g*8+7
    {
        float acc[8];
        #pragma unroll
        for (int j = 0; j < 8; ++j) acc[j] = bq[g * 8 + j];
        #pragma unroll 4
        for (int c = 0; c < CC; ++c) {
            const float x = skb[(size_t)c * NN];
            #pragma unroll
            for (int j = 0; j < 8; ++j) acc[j] += Wq[(g * 8 + j) * CC + c] * x;
        }
        #pragma unroll
        for (int j = 0; j < 8; ++j)
            qw[((size_t)b * DQK + g * 8 + j) * NN + n] = acc[j];
    }
    // ---- k
    {
        float acc[8];
        #pragma unroll
        for (int j = 0; j < 8; ++j) acc[j] = bk[g * 8 + j];
        #pragma unroll 4
        for (int c = 0; c < CC; ++c) {
            const float x = exb[(size_t)c * NN];
            #pragma unroll
            for (int j = 0; j < 8; ++j) acc[j] += Wk[(g * 8 + j) * CC + c] * x;
        }
        #pragma unroll
        for (int j = 0; j < 8; ++j)
            kw[((size_t)b * DQK + g * 8 + j) * NN + n] = acc[j];
    }
    // ---- v: outputs o = g*64 + vc*8 + j  (256 total across 4 groups)
    #pragma unroll 1
    for (int vc = 0; vc < 8; ++vc) {
        const int o0 = g * 64 + vc * 8;
        float acc[8];
        #pragma unroll
        for (int j = 0; j < 8; ++j) acc[j] = bv[o0 + j];
        #pragma unroll 4
        for (int c = 0; c < CC; ++c) {
            const float x = exb[(size_t)c * NN];
            #pragma unroll
            for (int j = 0; j < 8; ++j) acc[j] += Wv[(o0 + j) * CC + c] * x;
        }
        #pragma unroll
        for (int j = 0; j < 8; ++j)
            vw[((size_t)b * CC + o0 + j) * NN + n] = f2bf(acc[j]);
    }
}

// ---------------------------------------------------------------------------
// K2: energy + softmax, one block per (b, 8 m-rows). Energy rows staged bf16
// in 64 KB LDS (2 blocks/CU). k[b] (512 KB fp32) is read once per block and
// stays L2-resident; q[b][d][m0..m0+7] are wave-uniform scalar loads.
// Attention written fp32 straight into its d_out slot.
// ---------------------------------------------------------------------------
#define MT 8
__global__ __launch_bounds__(256) void k_attn(
    const float* __restrict__ qw, const float* __restrict__ kw,
    float* __restrict__ att)
{
    __shared__ unsigned short e[MT][NN];   // 64 KB
    __shared__ float red[8];
    const int t  = threadIdx.x;
    const int b  = blockIdx.y;
    const int m0 = blockIdx.x * MT;
    const float* qb = qw + (size_t)b * DQK * NN + m0;   // qb[d*NN + m]
    const float* kb = kw + (size_t)b * DQK * NN;

    // phase 1: energy rows -> LDS (bf16)
    #pragma unroll 1
    for (int i = 0; i < 16; ++i) {
        const int n = i * 256 + t;
        float acc[MT];
        #pragma unroll
        for (int m = 0; m < MT; ++m) acc[m] = 0.f;
        #pragma unroll 8
        for (int d = 0; d < DQK; ++d) {
            const float kv = kb[(size_t)d * NN + n];
            #pragma unroll
            for (int m = 0; m < MT; ++m) acc[m] += qb[(size_t)d * NN + m] * kv;
        }
        #pragma unroll
        for (int m = 0; m < MT; ++m) e[m][n] = f2bf(acc[m] * SCALE);
    }
    __syncthreads();

    // phase 2: per-row softmax + attention store
    const int lane = t & 63, wid = t >> 6;
    float* ab = att + (size_t)b * NN * NN + (size_t)m0 * NN;
    #pragma unroll 1
    for (int m = 0; m < MT; ++m) {
        float lm = -3.0e38f;
        for (int i = 0; i < 16; ++i) lm = fmaxf(lm, bf2f(e[m][i * 256 + t]));
        #pragma unroll
        for (int off = 32; off > 0; off >>= 1) lm = fmaxf(lm, __shfl_xor(lm, off));
        if (lane == 0) red[wid] = lm;
        __syncthreads();
        const float rmax = fmaxf(fmaxf(red[0], red[1]), fmaxf(red[2], red[3]));
        __syncthreads();
        float s = 0.f;
        for (int i = 0; i < 16; ++i) s += __expf(bf2f(e[m][i * 256 + t]) - rmax);
        #pragma unroll
        for (int off = 32; off > 0; off >>= 1) s += __shfl_xor(s, off);
        if (lane == 0) red[wid] = s;
        __syncthreads();
        const float inv = 1.f / (red[0] + red[1] + red[2] + red[3]);
        __syncthreads();
        for (int i = 0; i < 16; ++i) {
            const int n = i * 256 + t;
            ab[(size_t)m * NN + n] = __expf(bf2f(e[m][n]) - rmax) * inv;
        }
    }
}

// ---------------------------------------------------------------------------
// K3: texture[b,c,m] = sum_n v[b,c,n] * att[b,m,n], via bf16 MFMA 16x16x32.
// M-dim = c (A = V), N-dim = m (B = attention rows), K = n. One MFMA per
// 32-wide k-chunk. No LDS: A frags are 16B direct loads from bf16 v ws;
// B frags are 2x float4 loads of attention + inline RNE convert.
// Block = 4 waves; wave w owns c in [64w,64w+64), block owns 64 m. Epilogue
// adds sketches. grid (NN/64, BB).
// ---------------------------------------------------------------------------
__global__ __launch_bounds__(256) void k_tex(
    const unsigned short* __restrict__ vw,
    const float* __restrict__ att,
    const float* __restrict__ sk,
    float* __restrict__ outp, float* __restrict__ tex)
{
    const int t    = threadIdx.x;
    const int w    = t >> 6;
    const int lane = t & 63;
    const int lc   = lane & 15;      // A: m-row (=c), B: n-col (=m), D: col (=m)
    const int q    = lane >> 4;      // quad: k-offset q*8 (A/B), row-offset q*4 (D)
    const int b    = blockIdx.y;
    const int mb   = blockIdx.x * 64;
    const unsigned short* vb = vw + (size_t)b * CC * NN;
    const float* ab = att + (size_t)b * NN * NN;

    f32x4 acc[4][4];
    #pragma unroll
    for (int i = 0; i < 4; ++i)
        #pragma unroll
        for (int j = 0; j < 4; ++j)
            acc[i][j] = (f32x4){0.f, 0.f, 0.f, 0.f};

    const int c0 = w * 64 + lc;
    const int m0 = mb + lc;

    for (int n0 = 0; n0 < NN; n0 += 32) {
        bf16x8 vf[4];
        #pragma unroll
        for (int sc = 0; sc < 4; ++sc) {
            const unsigned short* p = vb + (size_t)(c0 + sc * 16) * NN + n0 + q * 8;
            vf[sc] = *(const bf16x8*)p;               // 16B load: V[c][n0+q*8 .. +8)
        }
        bf16x8 af[4];
        #pragma unroll
        for (int sm = 0; sm < 4; ++sm) {
            const float* p = ab + (size_t)(m0 + sm * 16) * NN + n0 + q * 8;
            const float4 x0 = *(const float4*)p;
            const float4 x1 = *(const float4*)(p + 4);
            union { bf16x8 v; unsigned short s[8]; } u;
            u.s[0] = f2bf(x0.x); u.s[1] = f2bf(x0.y);
            u.s[2] = f2bf(x0.z); u.s[3] = f2bf(x0.w);
            u.s[4] = f2bf(x1.x); u.s[5] = f2bf(x1.y);
            u.s[6] = f2bf(x1.z); u.s[7] = f2bf(x1.w);
            af[sm] = u.v;
        }
        #pragma unroll
        for (int sc = 0; sc < 4; ++sc)
            #pragma unroll
            for (int sm = 0; sm < 4; ++sm)
                acc[sc][sm] = __builtin_amdgcn_mfma_f32_16x16x32_bf16(
                    vf[sc], af[sm], acc[sc][sm], 0, 0, 0);
    }

    // epilogue: D[row=c within tile][col=m], row = q*4 + reg
    #pragma unroll
    for (int sc = 0; sc < 4; ++sc) {
        #pragma unroll
        for (int sm = 0; sm < 4; ++sm) {
            #pragma unroll
            for (int r = 0; r < 4; ++r) {
                const int c = w * 64 + sc * 16 + q * 4 + r;
                const int m = mb + sm * 16 + lc;
                const size_t idx = ((size_t)b * CC + c) * NN + m;
                const float tv = acc[sc][sm][r];
                tex[idx]  = tv;
                outp[idx] = tv + sk[idx];
            }
        }
    }
}

// ---------------------------------------------------------------------------
extern "C" void kernel_launch(void* const* d_in, const int* in_sizes, int n_in,
                              void* d_out, int out_size, void* d_ws, size_t ws_size,
                              hipStream_t stream)
{
    const float* sk = (const float*)d_in[0];
    const float* ex = (const float*)d_in[1];
    const float* Wq = (const float*)d_in[2];
    const float* bq = (const float*)d_in[3];
    const float* Wk = (const float*)d_in[4];
    const float* bk = (const float*)d_in[5];
    const float* Wv = (const float*)d_in[6];
    const float* bv = (const float*)d_in[7];

    float* outp = (float*)d_out;                         // [B,C,N]
    float* tex  = outp + (size_t)BB * CC * NN;           // [B,C,N]
    float* att  = tex  + (size_t)BB * CC * NN;           // [B,N,N]

    float* qw = (float*)d_ws;                            // [B,32,N] fp32, 4 MB
    float* kw = qw + (size_t)BB * DQK * NN;              // [B,32,N] fp32, 4 MB
    unsigned short* vw = (unsigned short*)(kw + (size_t)BB * DQK * NN); // [B,C,N] bf16, 16 MB

    k_qkv<<<dim3(NN / 64, BB), 256, 0, stream>>>(sk, ex, Wq, bq, Wk, bk, Wv, bv,
                                                 qw, kw, vw);
    k_attn<<<dim3(NN / MT, BB), 256, 0, stream>>>(qw, kw, att);
    k_tex<<<dim3(NN / 64, BB), 256, 0, stream>>>(vw, att, sk, outp, tex);
}